// Round 9
// baseline (105.227 us; speedup 1.0000x reference)
//
#include <hip/hip_runtime.h>
#include <hip/hip_bf16.h>

#define NB 2
#define ND 1024
#define NL 4096
#define NFS 4
#define NDEPTH 11
#define LN_EPS 1e-5f

#define BM 128
#define BN 128
#define BK 32
#define NKI (ND / BK)
#define ASZ (BM * BK)  // shorts per A (or B) buffer

#define CPAD 3072          // f16 elements of zero pad (lev10 reads back 3*1024)
#define CBUF (CPAD + NL)   // 7168 f16 = 14336 B

typedef __bf16 bf16x8 __attribute__((ext_vector_type(8)));
typedef float f32x4 __attribute__((ext_vector_type(4)));
typedef _Float16 half8 __attribute__((ext_vector_type(8)));

__device__ __forceinline__ unsigned short f2bf(float f) {
    __hip_bfloat16 h = __float2bfloat16(f);
    unsigned short u;
    __builtin_memcpy(&u, &h, 2);
    return u;
}

__device__ __forceinline__ float bf2f(unsigned short u) {
    unsigned int ui = (unsigned int)u << 16;
    float f;
    __builtin_memcpy(&f, &ui, 4);
    return f;
}

__device__ __forceinline__ unsigned int pack2bf(float lo, float hi) {
    return (unsigned int)f2bf(lo) | ((unsigned int)f2bf(hi) << 16);
}

// fast sigmoid: v_exp + raw v_rcp (avoids IEEE div sequence)
__device__ __forceinline__ float sigm(float v) {
    return __builtin_amdgcn_rcpf(1.f + __expf(-v));
}

// async global->LDS, 16B per lane (wave-uniform LDS base + lane*16)
__device__ __forceinline__ void llds16(const void* g, void* l) {
    __builtin_amdgcn_global_load_lds(
        (const __attribute__((address_space(1))) unsigned int*)g,
        (__attribute__((address_space(3))) unsigned int*)l, 16, 0, 0);
}

// ---------------------------------------------------------------- K0: W -> bf16
__global__ __launch_bounds__(256) void wconv_kernel(const float* __restrict__ w,
                                                    unsigned short* __restrict__ wbf) {
    const int idx8 = (blockIdx.x * 256 + threadIdx.x) * 8;
    const float4 v0 = *reinterpret_cast<const float4*>(w + idx8);
    const float4 v1 = *reinterpret_cast<const float4*>(w + idx8 + 4);
    uint4 o;
    o.x = pack2bf(v0.x, v0.y);
    o.y = pack2bf(v0.z, v0.w);
    o.z = pack2bf(v1.x, v1.y);
    o.w = pack2bf(v1.z, v1.w);
    *reinterpret_cast<uint4*>(wbf + idx8) = o;
}

// ------------------------------------------------- K1: dilated conv cascade + gating
// f16-packed: one block per (b*ND + d) row; 512 threads, thread t owns 8 contiguous
// positions [t*8, t*8+8) held as one half8 (4 VGPRs). Conv arithmetic is v_pk_fma_f16
// (2 muls/instr); every tap-set for dil>=8 is ONE aligned ds_read_b128 (8 taps);
// dil=1,2,4 use static shufflevector mixes of two adjacent blocks. Single in-place
// LDS f16 buffer (14.3 KiB) with 3072-elem zero pad; 2 barriers/level. Gate
// (sigmoid*b) stays f32. Lev 10 (dil=1024): a-conv only (b_list[10] unused).
__global__ __launch_bounds__(512, 8) void conv_cascade_kernel(const float* __restrict__ x,
                                                              const float* __restrict__ h0,
                                                              const float* __restrict__ h1,
                                                              unsigned short* __restrict__ ybf) {
    __shared__ _Float16 a_sh[CBUF];  // 14336 B
    const int row = blockIdx.x;      // b*ND + d
    const int d = row & (ND - 1);
    const int t = threadIdx.x;

    // zero the pad (3072 f16 = 384 half8); never written again
    if (t < CPAD / 8) *reinterpret_cast<half8*>(&a_sh[t * 8]) = (half8)0;

    const float* xrow = x + (size_t)row * NL;

    _Float16 h0c[NFS], h1c[NFS];
#pragma unroll
    for (int k = 0; k < NFS; ++k) {
        h0c[k] = (_Float16)h0[d * NFS + k];
        h1c[k] = (_Float16)h1[d * NFS + k];
    }

    // load x[t*8..t*8+8), convert to f16
    half8 cur;
    {
        const float4 v0 = *reinterpret_cast<const float4*>(xrow + t * 8);
        const float4 v1 = *reinterpret_cast<const float4*>(xrow + t * 8 + 4);
        cur[0] = (_Float16)v0.x; cur[1] = (_Float16)v0.y;
        cur[2] = (_Float16)v0.z; cur[3] = (_Float16)v0.w;
        cur[4] = (_Float16)v1.x; cur[5] = (_Float16)v1.y;
        cur[6] = (_Float16)v1.z; cur[7] = (_Float16)v1.w;
    }
    const int A = CPAD + t * 8;
    *reinterpret_cast<half8*>(&a_sh[A]) = cur;

    float yacc[8];
    half8 bprev = (half8)0;
#pragma unroll
    for (int j = 0; j < 8; ++j) yacc[j] = 0.f;
    __syncthreads();

    half8 an, bn;

#define CONV_MATH(a1, a2, a3)                                       \
    an = cur * h0c[3] + (a1)*h0c[2] + (a2)*h0c[1] + (a3)*h0c[0];    \
    bn = cur * h1c[3] + (a1)*h1c[2] + (a2)*h1c[1] + (a3)*h1c[0];

#define CONV_FIN(SC)                                                \
    {                                                               \
        *reinterpret_cast<half8*>(&a_sh[A]) = an;                   \
        if ((SC) > 0.f) {                                           \
            _Pragma("unroll") for (int j = 0; j < 8; ++j)           \
                yacc[j] += (SC)*sigm((float)an[j]) * (float)bprev[j]; \
        }                                                           \
        cur = an;                                                   \
        bprev = bn;                                                 \
    }

    // ---- lev 0 (dil=1): one extra block read, static shifts
    {
        const half8 m = *reinterpret_cast<const half8*>(&a_sh[A - 8]);
        const half8 a1 = __builtin_shufflevector(m, cur, 7, 8, 9, 10, 11, 12, 13, 14);
        const half8 a2 = __builtin_shufflevector(m, cur, 6, 7, 8, 9, 10, 11, 12, 13);
        const half8 a3 = __builtin_shufflevector(m, cur, 5, 6, 7, 8, 9, 10, 11, 12);
        CONV_MATH(a1, a2, a3)
        __syncthreads();
        CONV_FIN(0.f)
        __syncthreads();
    }

    // ---- lev 1 (dil=2): gate x2
    {
        const half8 m = *reinterpret_cast<const half8*>(&a_sh[A - 8]);
        const half8 a1 = __builtin_shufflevector(m, cur, 6, 7, 8, 9, 10, 11, 12, 13);
        const half8 a2 = __builtin_shufflevector(m, cur, 4, 5, 6, 7, 8, 9, 10, 11);
        const half8 a3 = __builtin_shufflevector(m, cur, 2, 3, 4, 5, 6, 7, 8, 9);
        CONV_MATH(a1, a2, a3)
        __syncthreads();
        CONV_FIN(2.f)
        __syncthreads();
    }

    // ---- lev 2 (dil=4): two extra block reads
    {
        const half8 m = *reinterpret_cast<const half8*>(&a_sh[A - 8]);
        const half8 m2 = *reinterpret_cast<const half8*>(&a_sh[A - 16]);
        const half8 a1 = __builtin_shufflevector(m, cur, 4, 5, 6, 7, 8, 9, 10, 11);
        const half8 a2 = m;
        const half8 a3 = __builtin_shufflevector(m2, m, 4, 5, 6, 7, 8, 9, 10, 11);
        CONV_MATH(a1, a2, a3)
        __syncthreads();
        CONV_FIN(1.f)
        __syncthreads();
    }

    // ---- lev 3..9 (dil=8..512): 3 direct aligned half8 reads
    int dil = 8;
#pragma unroll 1
    for (int lev = 3; lev <= 9; ++lev) {
        const half8 a1 = *reinterpret_cast<const half8*>(&a_sh[A - dil]);
        const half8 a2 = *reinterpret_cast<const half8*>(&a_sh[A - 2 * dil]);
        const half8 a3 = *reinterpret_cast<const half8*>(&a_sh[A - 3 * dil]);
        CONV_MATH(a1, a2, a3)
        __syncthreads();
        CONV_FIN(1.f)
        dil <<= 1;
        __syncthreads();
    }

    // ---- lev 10 (dil=1024): a-conv only (b_list[10] dead), no write-back
    {
        const half8 a1 = *reinterpret_cast<const half8*>(&a_sh[A - 1024]);
        const half8 a2 = *reinterpret_cast<const half8*>(&a_sh[A - 2048]);
        const half8 a3 = *reinterpret_cast<const half8*>(&a_sh[A - 3072]);
        an = cur * h0c[3] + a1 * h0c[2] + a2 * h0c[1] + a3 * h0c[0];
#pragma unroll
        for (int j = 0; j < 8; ++j)
            yacc[j] += sigm((float)an[j]) * (float)bprev[j];
    }
#undef CONV_MATH
#undef CONV_FIN

    uint4 o;
    o.x = pack2bf(yacc[0], yacc[1]);
    o.y = pack2bf(yacc[2], yacc[3]);
    o.z = pack2bf(yacc[4], yacc[5]);
    o.w = pack2bf(yacc[6], yacc[7]);
    *reinterpret_cast<uint4*>(ybf + (size_t)row * NL + t * 8) = o;
}

// ------------------------------------------- K2: y [b][c][l] bf16 -> yT [b][l][c] bf16
__global__ __launch_bounds__(256) void transpose_kernel(const unsigned short* __restrict__ ybf,
                                                        unsigned short* __restrict__ yT) {
    __shared__ unsigned short tile[64][66];
    const int l0 = blockIdx.x * 64;
    const int c0 = blockIdx.y * 64;
    const int b = blockIdx.z;
    const int t = threadIdx.x;
    const int li = t & 63, cg = t >> 6;
#pragma unroll
    for (int k = 0; k < 16; ++k) {
        const int ci = cg * 16 + k;
        tile[ci][li] = ybf[(size_t)(b * ND + c0 + ci) * NL + l0 + li];
    }
    __syncthreads();
    const int ci2 = t & 63, lg = t >> 6;
#pragma unroll
    for (int k = 0; k < 16; ++k) {
        const int li2 = lg * 16 + k;
        yT[((size_t)b * NL + l0 + li2) * ND + c0 + ci2] = tile[ci2][li2];
    }
}

// --------------------------- K3: mixed[b][o][l] = bf16( (W @ y)[o][l] + b_mix[o] )
// ring-3 LDS staging with counted vmcnt(4): 2 tiles in flight, never drained to 0
// inside the loop.
__global__ __launch_bounds__(256) void gemm_kernel(const unsigned short* __restrict__ wbf,
                                                   const unsigned short* __restrict__ yT,
                                                   const float* __restrict__ bmix,
                                                   unsigned short* __restrict__ mixed) {
    __shared__ unsigned short As[3][BM][BK];  // 24 KiB
    __shared__ unsigned short Bs[3][BN][BK];  // 24 KiB

    const int n0 = blockIdx.x * BN;
    const int m0 = blockIdx.y * BM;
    const int b = blockIdx.z;
    const int t = threadIdx.x;
    const int lane = t & 63, wid = t >> 6;
    const int wr = wid >> 1, wc = wid & 1;  // 2x2 waves, each 64x64
    const int fr = lane & 15;
    const int fk = (lane >> 4) * 8;

    const int srow = wid * 32 + (lane >> 2);
    const int sk = (lane & 3) * 8;
    const unsigned short* Ag = wbf + (size_t)(m0 + srow) * ND + sk;
    const unsigned short* Bg = yT + ((size_t)b * NL + n0 + srow) * ND + sk;
    unsigned short* A0 = &As[0][0][0];
    unsigned short* B0 = &Bs[0][0][0];
    unsigned short* AsW = A0 + wid * 32 * BK;
    unsigned short* BsW = B0 + wid * 32 * BK;

#define STAGE(bo, kt)                           \
    llds16(Ag + (kt), AsW + (bo));              \
    llds16(Ag + (kt) + 16 * ND, AsW + (bo) + 16 * BK); \
    llds16(Bg + (kt), BsW + (bo));              \
    llds16(Bg + (kt) + 16 * ND, BsW + (bo) + 16 * BK);

    f32x4 acc[4][4];
#pragma unroll
    for (int mi = 0; mi < 4; ++mi)
#pragma unroll
        for (int ni = 0; ni < 4; ++ni)
            acc[mi][ni] = (f32x4){0.f, 0.f, 0.f, 0.f};

    // prologue: stage tiles 0,1 into bufs 0,1 (8 loads outstanding)
    STAGE(0, 0)
    STAGE(ASZ, BK)

    int bc = 0;   // compute buffer index
    int bs = 2;   // stage buffer index
#pragma unroll 1
    for (int ki = 0; ki < NKI; ++ki) {
        if (ki + 1 < NKI) {
            asm volatile("s_waitcnt vmcnt(4)" ::: "memory");  // tile ki landed
        } else {
            asm volatile("s_waitcnt vmcnt(0)" ::: "memory");
        }
        __builtin_amdgcn_s_barrier();
        __builtin_amdgcn_sched_barrier(0);

        if (ki + 2 < NKI) {
            const int bo = bs * ASZ;
            const int kt = (ki + 2) * BK;
            STAGE(bo, kt)
        }

        const int bco = bc * ASZ;
        bf16x8 af[4], bv[4];
#pragma unroll
        for (int mi = 0; mi < 4; ++mi)
            af[mi] = *reinterpret_cast<const bf16x8*>(A0 + bco + (wr * 64 + mi * 16 + fr) * BK + fk);
#pragma unroll
        for (int ni = 0; ni < 4; ++ni)
            bv[ni] = *reinterpret_cast<const bf16x8*>(B0 + bco + (wc * 64 + ni * 16 + fr) * BK + fk);
#pragma unroll
        for (int mi = 0; mi < 4; ++mi)
#pragma unroll
            for (int ni = 0; ni < 4; ++ni)
                acc[mi][ni] = __builtin_amdgcn_mfma_f32_16x16x32_bf16(af[mi], bv[ni],
                                                                      acc[mi][ni], 0, 0, 0);
        bc = (bc == 2) ? 0 : bc + 1;
        bs = (bs == 2) ? 0 : bs + 1;
    }
#undef STAGE

    // epilogue: D[row][col], col = lane&15, row = (lane>>4)*4 + r
    const size_t bbase = (size_t)b * ND * NL;
#pragma unroll
    for (int mi = 0; mi < 4; ++mi) {
#pragma unroll
        for (int r = 0; r < 4; ++r) {
            const int o = m0 + wr * 64 + mi * 16 + (lane >> 4) * 4 + r;
            const float bm = bmix[o];
            const size_t rowbase = bbase + (size_t)o * NL;
#pragma unroll
            for (int ni = 0; ni < 4; ++ni) {
                const int l = n0 + wc * 64 + ni * 16 + fr;
                mixed[rowbase + l] = f2bf(acc[mi][ni][r] + bm);
            }
        }
    }
}

// ------------------------- K4: z = mixed + x (regs) -> LayerNorm over channels -> out
__global__ __launch_bounds__(512) void ln_kernel(const unsigned short* __restrict__ mixed,
                                                 const float* __restrict__ x,
                                                 const float* __restrict__ gamma,
                                                 const float* __restrict__ beta,
                                                 float* __restrict__ out) {
    const int b = blockIdx.y;
    const int l0 = blockIdx.x * 32;
    const int tl = threadIdx.x & 31, tg = threadIdx.x >> 5;  // 16 c-groups x 32 cols
    const size_t base = (size_t)b * ND * NL + l0 + tl;

    float zv[64];
    float s = 0.f, q = 0.f;
#pragma unroll
    for (int j = 0; j < 64; ++j) {
        const size_t idx = base + (size_t)(tg + j * 16) * NL;
        const float v = bf2f(mixed[idx]) + x[idx];
        zv[j] = v;
        s += v;
        q += v * v;
    }

    __shared__ float sred[16][33], qred[16][33];
    __shared__ float mu_s[32], rs_s[32];
    sred[tg][tl] = s;
    qred[tg][tl] = q;
    __syncthreads();
    if (tg == 0) {
        float S = 0.f, Q = 0.f;
#pragma unroll
        for (int g = 0; g < 16; ++g) {
            S += sred[g][tl];
            Q += qred[g][tl];
        }
        const float mu = S * (1.f / ND);
        const float var = Q * (1.f / ND) - mu * mu;
        mu_s[tl] = mu;
        rs_s[tl] = rsqrtf(var + LN_EPS);
    }
    __syncthreads();
    const float mu = mu_s[tl], rs = rs_s[tl];
#pragma unroll
    for (int j = 0; j < 64; ++j) {
        const int c = tg + j * 16;
        out[base + (size_t)c * NL] = (zv[j] - mu) * rs * gamma[c] + beta[c];
    }
}

extern "C" void kernel_launch(void* const* d_in, const int* in_sizes, int n_in,
                              void* d_out, int out_size, void* d_ws, size_t ws_size,
                              hipStream_t stream) {
    (void)in_sizes; (void)n_in; (void)out_size; (void)ws_size;
    const float* x = (const float*)d_in[0];
    const float* h0 = (const float*)d_in[1];
    const float* h1 = (const float*)d_in[2];
    const float* wmix = (const float*)d_in[3];
    const float* bmix = (const float*)d_in[4];
    const float* gamma = (const float*)d_in[5];
    const float* beta = (const float*)d_in[6];
    float* out = (float*)d_out;

    char* ws = (char*)d_ws;
    unsigned short* ybf = (unsigned short*)(ws);                              // 16 MiB
    unsigned short* yT = (unsigned short*)(ws + (size_t)16 * 1024 * 1024);    // 16 MiB
    unsigned short* wbf = (unsigned short*)(ws + (size_t)32 * 1024 * 1024);   // 2 MiB
    unsigned short* mixed = (unsigned short*)(ws + (size_t)34 * 1024 * 1024); // 16 MiB

    wconv_kernel<<<dim3(ND * ND / (256 * 8)), 256, 0, stream>>>(wmix, wbf);
    conv_cascade_kernel<<<dim3(NB * ND), 512, 0, stream>>>(x, h0, h1, ybf);
    transpose_kernel<<<dim3(NL / 64, ND / 64, NB), 256, 0, stream>>>(ybf, yT);
    gemm_kernel<<<dim3(NL / BN, ND / BM, NB), 256, 0, stream>>>(wbf, yT, bmix, mixed);
    ln_kernel<<<dim3(NL / 32, NB), 512, 0, stream>>>(mixed, x, gamma, beta, out);
}